// Round 9
// baseline (456.808 us; speedup 1.0000x reference)
//
#include <hip/hip_runtime.h>

typedef short bf16x8 __attribute__((ext_vector_type(8)));
typedef float f32x4  __attribute__((ext_vector_type(4)));
typedef unsigned short u16x4 __attribute__((ext_vector_type(4)));

#define BSTR 584   // ushorts per co row in Bs: 576 + 8 pad
#define LSTR 296   // fallback kernel LDS stride

__device__ __forceinline__ unsigned short f2bf(float f) {
    unsigned u = __float_as_uint(f);
    return (unsigned short)((u + 0x7FFFu + ((u >> 16) & 1u)) >> 16);  // RNE
}

// ---- Kernel 1: x[bc][hw] f32 -> xT[hw][bc] bf16 ----
__global__ __launch_bounds__(256)
void transpose_in(const float* __restrict__ x, unsigned short* __restrict__ xT) {
    __shared__ float tile[64][65];
    const int t  = threadIdx.x;
    const int tr = blockIdx.x >> 6, tc = blockIdx.x & 63;
    const int r0 = tr << 6, c0 = tc << 6;
    const int cc = (t & 15) << 2;
    #pragma unroll
    for (int q = 0; q < 4; ++q) {
        const int rr = (t >> 4) + (q << 4);
        const f32x4 v = __builtin_nontemporal_load(
            (const f32x4*)&x[(size_t)(r0 + rr) * 4096 + c0 + cc]);
        tile[rr][cc + 0] = v[0]; tile[rr][cc + 1] = v[1];
        tile[rr][cc + 2] = v[2]; tile[rr][cc + 3] = v[3];
    }
    __syncthreads();
    #pragma unroll
    for (int q = 0; q < 4; ++q) {
        const int rr = (t >> 4) + (q << 4);
        u16x4 o;
        o[0] = f2bf(tile[cc + 0][rr]); o[1] = f2bf(tile[cc + 1][rr]);
        o[2] = f2bf(tile[cc + 2][rr]); o[3] = f2bf(tile[cc + 3][rr]);
        *(u16x4*)&xT[(size_t)(c0 + rr) * 4096 + r0 + cc] = o;
    }
}

// ---- Kernel 2 (fused): block = (h, 16-co group, 32-w half); no output transpose ----
__global__ __launch_bounds__(256, 2)
void lc_fused(const unsigned short* __restrict__ xT, const float* __restrict__ wt,
              float* __restrict__ out) {
    __shared__ __align__(16) unsigned short Bs[16 * BSTR];        // 18688 B
    __shared__ __align__(16) unsigned short OutS[16 * 64 * 16];   // 32768 B

    const int bid = blockIdx.x;                 // 512 blocks
    const int h     = (bid & 7) * 8 + (bid >> 6);
    const int sub   = (bid >> 3) & 7;
    const int cog   = sub >> 1;
    const int whalf = sub & 1;
    const int w0    = whalf << 5;

    const int t    = threadIdx.x;
    const int lane = t & 63;
    const int wv   = t >> 6;          // wave id = m-tile
    const int l15  = lane & 15;
    const int kg   = lane >> 4;

    // weight staging: thread t owns 36 consecutive floats = 4 ci x 9 taps of row co_s
    const int co_s = t >> 4;
    const int fsg  = t & 15;
    const float* wbase = wt + (size_t)(h << 6) * 36864
                            + (size_t)(cog * 16 + co_s) * 576 + fsg * 36;

    f32x4  wreg[9];
    bf16x8 A[9][2];

    auto issueW = [&](int w) {
        const float* s = wbase + (size_t)w * 36864;
        #pragma unroll
        for (int i = 0; i < 9; ++i)
            wreg[i] = __builtin_nontemporal_load((const f32x4*)(s + (i << 2)));
    };
    auto writeB = [&]() {
        #pragma unroll
        for (int tap = 0; tap < 9; ++tap) {
            u16x4 o;   // (ci j, tap) = float fsg*36 + j*9 + tap
            o[0] = f2bf(wreg[(0  + tap) >> 2][(0  + tap) & 3]);
            o[1] = f2bf(wreg[(9  + tap) >> 2][(9  + tap) & 3]);
            o[2] = f2bf(wreg[(18 + tap) >> 2][(18 + tap) & 3]);
            o[3] = f2bf(wreg[(27 + tap) >> 2][(27 + tap) & 3]);
            *(u16x4*)&Bs[co_s * BSTR + tap * 64 + (fsg << 2)] = o;
        }
    };
    auto issueA = [&](int w) {
        #pragma unroll
        for (int tap = 0; tap < 9; ++tap) {
            const int y  = h + tap / 3 - 1;
            const int xx = w + tap % 3 - 1;
            const bool ok = ((unsigned)y < 64u) && ((unsigned)xx < 64u);
            const unsigned short* src = xT + (size_t)((y << 6) + xx) * 4096
                                           + (((wv << 4) + l15) << 6) + (kg << 3);
            #pragma unroll
            for (int c = 0; c < 2; ++c) {
                bf16x8 v = {0,0,0,0,0,0,0,0};
                if (ok) v = *(const bf16x8*)(src + (c << 5));
                A[tap][c] = v;
            }
        }
    };

    // prologue
    issueA(w0);
    issueW(w0);
    writeB();                 // B(w0)
    issueW(w0 + 1);
    __syncthreads();

    for (int wi = 0; wi < 32; ++wi) {
        const int w = w0 + wi;

        f32x4 a0 = {0.f,0.f,0.f,0.f}, a1 = {0.f,0.f,0.f,0.f};
        #pragma unroll
        for (int tap = 0; tap < 9; ++tap) {
            #pragma unroll
            for (int c = 0; c < 2; ++c) {
                const bf16x8 bfr = *(const bf16x8*)&Bs[l15 * BSTR + tap * 64
                                                       + (c << 5) + (kg << 3)];
                if (tap & 1) a1 = __builtin_amdgcn_mfma_f32_16x16x32_bf16(A[tap][c], bfr, a1, 0, 0, 0);
                else         a0 = __builtin_amdgcn_mfma_f32_16x16x32_bf16(A[tap][c], bfr, a0, 0, 0, 0);
            }
        }

        if (wi < 31) issueA(w + 1);          // refill A regs for next w (L2 hits)

        {   // result -> OutS staging tile
            const f32x4 r = a0 + a1;
            const int slot = w & 15;
            #pragma unroll
            for (int j = 0; j < 4; ++j)
                OutS[slot * 1024 + (((wv << 4) + (kg << 2) + j) << 4) + l15]
                    = f2bf(fmaxf(r[j], 0.f));
        }
        __syncthreads();                      // Bs(w) reads + OutS(w) stores done

        if (wi < 31) writeB();                // stage B(w+1)
        if (wi < 30) issueW(w + 2);

        if ((wi & 15) == 15) {                // flush 16 w: 1024 (b,col) pairs, 4/thread
            const int segw = w0 + (wi & 16);
            #pragma unroll
            for (int rep = 0; rep < 4; ++rep) {
                const int p = (t << 2) + rep; // pair = b*16 + col, p in 0..1023
                const int b = p >> 4, col = p & 15;
                float vals[16];
                #pragma unroll
                for (int u = 0; u < 16; ++u)
                    vals[u] = __uint_as_float(
                        (unsigned)OutS[u * 1024 + (b << 4) + col] << 16);
                float* dst = out + (size_t)((b << 6) + (cog << 4) + col) * 4096
                                 + (h << 6) + segw;
                #pragma unroll
                for (int g = 0; g < 4; ++g) {
                    f32x4 o = { vals[g*4], vals[g*4+1], vals[g*4+2], vals[g*4+3] };
                    __builtin_nontemporal_store(o, (f32x4*)(dst + (g << 2)));
                }
            }
        }
        __syncthreads();                      // Bs(w+1) visible; flush reads done
    }
}

// ---- Fallback (round-2 proven): direct gather + scattered write ----
__global__ __launch_bounds__(256, 4)
void lc_mfma(const float* __restrict__ x, const float* __restrict__ wt,
             float* __restrict__ out) {
    __shared__ __align__(16) unsigned short A[64 * LSTR];
    const int bid = blockIdx.x;
    const int swz = (bid & 7) * 512 + (bid >> 3);
    const int h   = swz >> 6;
    const int wq  = swz & 63;
    const int t    = threadIdx.x;
    const int lane = t & 63;
    const int wv   = t >> 6;
    const float* wloc = wt + (size_t)((h << 6) + wq) * 36864;
    const int co = (wv << 4) + (lane & 15);
    const int kg = lane >> 4;
    const float* wrow = wloc + co * 576 + (kg << 3);
    f32x4 acc[4] = {{0.f,0.f,0.f,0.f},{0.f,0.f,0.f,0.f},
                    {0.f,0.f,0.f,0.f},{0.f,0.f,0.f,0.f}};
    const int cil = t & 31;
    const int bro = t >> 5;
    for (int hs = 0; hs < 2; ++hs) {
        const int kbase = hs * 288;
        f32x4 pb[3][2];
        pb[0][0] = __builtin_nontemporal_load((const f32x4*)(wrow + kbase + 0));
        pb[0][1] = __builtin_nontemporal_load((const f32x4*)(wrow + kbase + 4));
        pb[1][0] = __builtin_nontemporal_load((const f32x4*)(wrow + kbase + 32));
        pb[1][1] = __builtin_nontemporal_load((const f32x4*)(wrow + kbase + 36));
        {
            const int ci = (hs << 5) + cil;
            for (int p = 0; p < 8; ++p) {
                const int b = (p << 3) + bro;
                const float* xb = x + ((size_t)((b << 6) + ci) << 12);
                unsigned short* dst = &A[b * LSTR + cil * 9];
                #pragma unroll
                for (int dy = 0; dy < 3; ++dy) {
                    const int y = h + dy - 1;
                    const bool yok = (unsigned)y < 64u;
                    #pragma unroll
                    for (int dx = 0; dx < 3; ++dx) {
                        const int xx = wq + dx - 1;
                        float v = 0.f;
                        if (yok && (unsigned)xx < 64u) v = xb[(y << 6) + xx];
                        dst[dy * 3 + dx] = f2bf(v);
                    }
                }
            }
        }
        __syncthreads();
        #pragma unroll
        for (int ks = 0; ks < 9; ++ks) {
            const int cur = ks % 3;
            const int nxt = (ks + 2) % 3;
            if (ks < 7) {
                const float* np = wrow + kbase + (ks + 2) * 32;
                pb[nxt][0] = __builtin_nontemporal_load((const f32x4*)(np));
                pb[nxt][1] = __builtin_nontemporal_load((const f32x4*)(np + 4));
            }
            const f32x4 lo = pb[cur][0], hi = pb[cur][1];
            bf16x8 bf;
            bf[0] = (short)f2bf(lo[0]); bf[1] = (short)f2bf(lo[1]);
            bf[2] = (short)f2bf(lo[2]); bf[3] = (short)f2bf(lo[3]);
            bf[4] = (short)f2bf(hi[0]); bf[5] = (short)f2bf(hi[1]);
            bf[6] = (short)f2bf(hi[2]); bf[7] = (short)f2bf(hi[3]);
            const int kk = (ks << 5) + (kg << 3);
            #pragma unroll
            for (int mt = 0; mt < 4; ++mt) {
                const bf16x8 afl = *(const bf16x8*)&A[((mt << 4) + (lane & 15)) * LSTR + kk];
                acc[mt] = __builtin_amdgcn_mfma_f32_16x16x32_bf16(afl, bf, acc[mt], 0, 0, 0);
            }
        }
        __syncthreads();
    }
    const int rg = lane >> 4;
    #pragma unroll
    for (int mt = 0; mt < 4; ++mt) {
        #pragma unroll
        for (int j = 0; j < 4; ++j) {
            const int b = (mt << 4) + (rg << 2) + j;
            out[(size_t)((b << 6) + co) * 4096 + (h << 6) + wq] = fmaxf(acc[mt][j], 0.f);
        }
    }
}

extern "C" void kernel_launch(void* const* d_in, const int* in_sizes, int n_in,
                              void* d_out, int out_size, void* d_ws, size_t ws_size,
                              hipStream_t stream) {
    const float* x  = (const float*)d_in[0];
    const float* wt = (const float*)d_in[1];
    float* out = (float*)d_out;

    const size_t xT_bytes = (size_t)4096 * 4096 * 2;   // 33.5 MB bf16

    if (ws_size >= xT_bytes) {
        unsigned short* xT = (unsigned short*)d_ws;
        hipLaunchKernelGGL(transpose_in, dim3(4096), dim3(256), 0, stream, x, xT);
        hipLaunchKernelGGL(lc_fused, dim3(512), dim3(256), 0, stream, xT, wt, out);
    } else {
        hipLaunchKernelGGL(lc_mfma, dim3(4096), dim3(256), 0, stream, x, wt, out);
    }
}

// Round 10
// 312.811 us; speedup vs baseline: 1.4603x; 1.4603x over previous
//
#include <hip/hip_runtime.h>

typedef short bf16x8 __attribute__((ext_vector_type(8)));
typedef float f32x4  __attribute__((ext_vector_type(4)));
typedef unsigned short u16x4 __attribute__((ext_vector_type(4)));

#define ASTR 296   // A row stride (ushorts): 288 + 8 pad (2-way bank alias = free)
#define BSTR 296   // B row stride (ushorts): 288 + 8 pad
#define LSTR 296   // fallback kernel

__device__ __forceinline__ unsigned short f2bf(float f) {
    unsigned u = __float_as_uint(f);
    return (unsigned short)((u + 0x7FFFu + ((u >> 16) & 1u)) >> 16);  // RNE
}

// ---- Kernel 1: x[bc][hw] f32 -> xT[hw][bc] bf16 ----
__global__ __launch_bounds__(256)
void transpose_in(const float* __restrict__ x, unsigned short* __restrict__ xT) {
    __shared__ float tile[64][65];
    const int t  = threadIdx.x;
    const int tr = blockIdx.x >> 6, tc = blockIdx.x & 63;
    const int r0 = tr << 6, c0 = tc << 6;
    const int cc = (t & 15) << 2;
    #pragma unroll
    for (int q = 0; q < 4; ++q) {
        const int rr = (t >> 4) + (q << 4);
        const f32x4 v = __builtin_nontemporal_load(
            (const f32x4*)&x[(size_t)(r0 + rr) * 4096 + c0 + cc]);
        tile[rr][cc + 0] = v[0]; tile[rr][cc + 1] = v[1];
        tile[rr][cc + 2] = v[2]; tile[rr][cc + 3] = v[3];
    }
    __syncthreads();
    #pragma unroll
    for (int q = 0; q < 4; ++q) {
        const int rr = (t >> 4) + (q << 4);
        u16x4 o;
        o[0] = f2bf(tile[cc + 0][rr]); o[1] = f2bf(tile[cc + 1][rr]);
        o[2] = f2bf(tile[cc + 2][rr]); o[3] = f2bf(tile[cc + 3][rr]);
        *(u16x4*)&xT[(size_t)(c0 + rr) * 4096 + r0 + cc] = o;
    }
}

// ---- Kernel 2: round-7 proven GEMM engine; epilogue writes f32 `out` directly.
// All 64 w-blocks of an h are co-resident on one XCD (swizzle), so the 16
// scattered 4B writes per out-line merge in that XCD's L2 -> full-line writebacks.
__global__ __launch_bounds__(256, 2)
void lc_main(const unsigned short* __restrict__ xT, const float* __restrict__ wt,
             float* __restrict__ out) {
    __shared__ __align__(16) unsigned short A[64 * ASTR];   // 37888 B
    __shared__ __align__(16) unsigned short B[32 * BSTR];   // 18944 B

    const int bid = blockIdx.x;
    const int swz = (bid & 7) * 512 + (bid >> 3);   // bijective XCD remap
    const int h = swz >> 6, wq = swz & 63;
    const int loc = (h << 6) + wq;

    const int t    = threadIdx.x;
    const int lane = t & 63;
    const int wv   = t >> 6;
    const int l15  = lane & 15;
    const int kg   = lane >> 4;

    const float* wloc = wt + (size_t)loc * 36864;

    // B staging map: thread t -> chunk row bco (0..31), granule oct (0..7)
    const int bco = t >> 3;
    const int oct = t & 7;

    // A staging map: b_st (0..63), cig (0..3)
    const int b_st = t >> 2;
    const int cig  = t & 3;

    // taps
    int tapr[9]; int tv[9];
    #pragma unroll
    for (int tap = 0; tap < 9; ++tap) {
        const int y = h + tap / 3 - 1, xx = wq + tap % 3 - 1;
        const int ok = ((unsigned)y < 64u) && ((unsigned)xx < 64u);
        tv[tap] = ok;
        tapr[tap] = ok ? ((y << 6) + xx) : 0;
    }

    f32x4 acc[2][2] = {{{0.f,0.f,0.f,0.f},{0.f,0.f,0.f,0.f}},
                       {{0.f,0.f,0.f,0.f},{0.f,0.f,0.f,0.f}}};
    f32x4  br[9];
    bf16x8 xr[9];

    auto issueB = [&](int hs, int ch) {
        const float* s = wloc + (size_t)(ch * 32 + bco) * 576 + hs * 288 + (oct << 2);
        #pragma unroll
        for (int i = 0; i < 9; ++i)
            br[i] = __builtin_nontemporal_load((const f32x4*)(s + (i << 5)));
    };
    auto writeB = [&]() {
        unsigned short* d = &B[bco * BSTR + (oct << 2)];
        #pragma unroll
        for (int i = 0; i < 9; ++i) {
            u16x4 o;
            o[0] = f2bf(br[i][0]); o[1] = f2bf(br[i][1]);
            o[2] = f2bf(br[i][2]); o[3] = f2bf(br[i][3]);
            *(u16x4*)&d[i << 5] = o;
        }
    };
    auto issueA = [&](int hs) {
        #pragma unroll
        for (int tap = 0; tap < 9; ++tap) {
            bf16x8 v = {0,0,0,0,0,0,0,0};
            if (tv[tap])
                v = *(const bf16x8*)&xT[(size_t)tapr[tap] * 4096 + (b_st << 6)
                                        + hs * 32 + (cig << 3)];
            xr[tap] = v;
        }
    };
    auto writeA = [&]() {
        unsigned short* d = &A[b_st * ASTR + cig * 72];
        #pragma unroll
        for (int tap = 0; tap < 9; ++tap)
            #pragma unroll
            for (int j = 0; j < 8; ++j)
                d[j * 9 + tap] = (unsigned short)xr[tap][j];
    };
    auto compute = [&](int ch) {
        const int arow0 = ((wv >> 1) * 32 + l15) * ASTR + (kg << 3);
        const int brow  = ((wv & 1) * 16 + l15) * BSTR + (kg << 3);
        #pragma unroll
        for (int ksl = 0; ksl < 9; ++ksl) {
            const int kk = ksl * 32;
            const bf16x8 bfr = *(const bf16x8*)&B[brow + kk];
            const bf16x8 a0  = *(const bf16x8*)&A[arow0 + kk];
            const bf16x8 a1  = *(const bf16x8*)&A[arow0 + 16 * ASTR + kk];
            acc[0][ch] = __builtin_amdgcn_mfma_f32_16x16x32_bf16(a0, bfr, acc[0][ch], 0, 0, 0);
            acc[1][ch] = __builtin_amdgcn_mfma_f32_16x16x32_bf16(a1, bfr, acc[1][ch], 0, 0, 0);
        }
    };

    // ---- T14 pipeline (round-7 proven): issue one phase ahead of every write ----
    issueB(0, 0); issueA(0);
    writeB(); writeA();
    issueB(0, 1);
    __syncthreads();
    compute(0);                       // (hs0, ch0); B01 in flight
    __syncthreads();
    writeB(); issueB(1, 0); issueA(1);
    __syncthreads();
    compute(1);                       // (hs0, ch1); B10+A1 in flight
    __syncthreads();
    writeB(); writeA();
    issueB(1, 1);
    __syncthreads();
    compute(0);                       // (hs1, ch0); B11 in flight
    __syncthreads();
    writeB();
    __syncthreads();
    compute(1);                       // (hs1, ch1)

    // epilogue: DIRECT f32 out, plain stores (L2-merge across same-h blocks)
    #pragma unroll
    for (int m2 = 0; m2 < 2; ++m2)
        #pragma unroll
        for (int ch = 0; ch < 2; ++ch)
            #pragma unroll
            for (int j = 0; j < 4; ++j) {
                const int b  = (wv >> 1) * 32 + m2 * 16 + (kg << 2) + j;
                const int co = ch * 32 + (wv & 1) * 16 + l15;
                out[(size_t)((b << 6) + co) * 4096 + loc] = fmaxf(acc[m2][ch][j], 0.f);
            }
}

// ---- Fallback (round-2 proven): direct gather + scattered write ----
__global__ __launch_bounds__(256, 4)
void lc_mfma(const float* __restrict__ x, const float* __restrict__ wt,
             float* __restrict__ out) {
    __shared__ __align__(16) unsigned short A[64 * LSTR];
    const int bid = blockIdx.x;
    const int swz = (bid & 7) * 512 + (bid >> 3);
    const int h   = swz >> 6;
    const int wq  = swz & 63;
    const int t    = threadIdx.x;
    const int lane = t & 63;
    const int wv   = t >> 6;
    const float* wloc = wt + (size_t)((h << 6) + wq) * 36864;
    const int co = (wv << 4) + (lane & 15);
    const int kg = lane >> 4;
    const float* wrow = wloc + co * 576 + (kg << 3);
    f32x4 acc[4] = {{0.f,0.f,0.f,0.f},{0.f,0.f,0.f,0.f},
                    {0.f,0.f,0.f,0.f},{0.f,0.f,0.f,0.f}};
    const int cil = t & 31;
    const int bro = t >> 5;
    for (int hs = 0; hs < 2; ++hs) {
        const int kbase = hs * 288;
        f32x4 pb[3][2];
        pb[0][0] = __builtin_nontemporal_load((const f32x4*)(wrow + kbase + 0));
        pb[0][1] = __builtin_nontemporal_load((const f32x4*)(wrow + kbase + 4));
        pb[1][0] = __builtin_nontemporal_load((const f32x4*)(wrow + kbase + 32));
        pb[1][1] = __builtin_nontemporal_load((const f32x4*)(wrow + kbase + 36));
        {
            const int ci = (hs << 5) + cil;
            for (int p = 0; p < 8; ++p) {
                const int b = (p << 3) + bro;
                const float* xb = x + ((size_t)((b << 6) + ci) << 12);
                unsigned short* dst = &A[b * LSTR + cil * 9];
                #pragma unroll
                for (int dy = 0; dy < 3; ++dy) {
                    const int y = h + dy - 1;
                    const bool yok = (unsigned)y < 64u;
                    #pragma unroll
                    for (int dx = 0; dx < 3; ++dx) {
                        const int xx = wq + dx - 1;
                        float v = 0.f;
                        if (yok && (unsigned)xx < 64u) v = xb[(y << 6) + xx];
                        dst[dy * 3 + dx] = f2bf(v);
                    }
                }
            }
        }
        __syncthreads();
        #pragma unroll
        for (int ks = 0; ks < 9; ++ks) {
            const int cur = ks % 3;
            const int nxt = (ks + 2) % 3;
            if (ks < 7) {
                const float* np = wrow + kbase + (ks + 2) * 32;
                pb[nxt][0] = __builtin_nontemporal_load((const f32x4*)(np));
                pb[nxt][1] = __builtin_nontemporal_load((const f32x4*)(np + 4));
            }
            const f32x4 lo = pb[cur][0], hi = pb[cur][1];
            bf16x8 bf;
            bf[0] = (short)f2bf(lo[0]); bf[1] = (short)f2bf(lo[1]);
            bf[2] = (short)f2bf(lo[2]); bf[3] = (short)f2bf(lo[3]);
            bf[4] = (short)f2bf(hi[0]); bf[5] = (short)f2bf(hi[1]);
            bf[6] = (short)f2bf(hi[2]); bf[7] = (short)f2bf(hi[3]);
            const int kk = (ks << 5) + (kg << 3);
            #pragma unroll
            for (int mt = 0; mt < 4; ++mt) {
                const bf16x8 afl = *(const bf16x8*)&A[((mt << 4) + (lane & 15)) * LSTR + kk];
                acc[mt] = __builtin_amdgcn_mfma_f32_16x16x32_bf16(afl, bf, acc[mt], 0, 0, 0);
            }
        }
        __syncthreads();
    }
    const int rg = lane >> 4;
    #pragma unroll
    for (int mt = 0; mt < 4; ++mt) {
        #pragma unroll
        for (int j = 0; j < 4; ++j) {
            const int b = (mt << 4) + (rg << 2) + j;
            out[(size_t)((b << 6) + co) * 4096 + (h << 6) + wq] = fmaxf(acc[mt][j], 0.f);
        }
    }
}

extern "C" void kernel_launch(void* const* d_in, const int* in_sizes, int n_in,
                              void* d_out, int out_size, void* d_ws, size_t ws_size,
                              hipStream_t stream) {
    const float* x  = (const float*)d_in[0];
    const float* wt = (const float*)d_in[1];
    float* out = (float*)d_out;

    const size_t xT_bytes = (size_t)4096 * 4096 * 2;   // 33.5 MB bf16

    if (ws_size >= xT_bytes) {
        unsigned short* xT = (unsigned short*)d_ws;
        hipLaunchKernelGGL(transpose_in, dim3(4096), dim3(256), 0, stream, x, xT);
        hipLaunchKernelGGL(lc_main, dim3(4096), dim3(256), 0, stream, xT, wt, out);
    } else {
        hipLaunchKernelGGL(lc_mfma, dim3(4096), dim3(256), 0, stream, x, wt, out);
    }
}

// Round 11
// 162.222 us; speedup vs baseline: 2.8160x; 1.9283x over previous
//
#include <hip/hip_runtime.h>

typedef short bf16x8 __attribute__((ext_vector_type(8)));
typedef float f32x4  __attribute__((ext_vector_type(4)));
typedef unsigned short u16x4 __attribute__((ext_vector_type(4)));

#define ASTR 296   // A row stride (ushorts): 288 + 8 pad
#define BSTR 296   // B row stride (ushorts): 288 + 8 pad
#define LSTR 296   // fallback kernel

__device__ __forceinline__ unsigned short f2bf(float f) {
    unsigned u = __float_as_uint(f);
    return (unsigned short)((u + 0x7FFFu + ((u >> 16) & 1u)) >> 16);  // RNE
}

// ---- Kernel 1: x[bc][hw] f32 -> xT[hw][bc] bf16 ----
__global__ __launch_bounds__(256)
void transpose_in(const float* __restrict__ x, unsigned short* __restrict__ xT) {
    __shared__ float tile[64][65];
    const int t  = threadIdx.x;
    const int tr = blockIdx.x >> 6, tc = blockIdx.x & 63;
    const int r0 = tr << 6, c0 = tc << 6;
    const int cc = (t & 15) << 2;
    #pragma unroll
    for (int q = 0; q < 4; ++q) {
        const int rr = (t >> 4) + (q << 4);
        const f32x4 v = __builtin_nontemporal_load(
            (const f32x4*)&x[(size_t)(r0 + rr) * 4096 + c0 + cc]);
        tile[rr][cc + 0] = v[0]; tile[rr][cc + 1] = v[1];
        tile[rr][cc + 2] = v[2]; tile[rr][cc + 3] = v[3];
    }
    __syncthreads();
    #pragma unroll
    for (int q = 0; q < 4; ++q) {
        const int rr = (t >> 4) + (q << 4);
        u16x4 o;
        o[0] = f2bf(tile[cc + 0][rr]); o[1] = f2bf(tile[cc + 1][rr]);
        o[2] = f2bf(tile[cc + 2][rr]); o[3] = f2bf(tile[cc + 3][rr]);
        *(u16x4*)&xT[(size_t)(c0 + rr) * 4096 + r0 + cc] = o;
    }
}

// ---- Kernel 3: outT[hw][bc] bf16 -> out[bc][hw] f32 ----
__global__ __launch_bounds__(256)
void transpose_out_bf(const unsigned short* __restrict__ src, float* __restrict__ dst) {
    __shared__ unsigned short tile[64][66];
    const int t  = threadIdx.x;
    const int tr = blockIdx.x >> 6, tc = blockIdx.x & 63;
    const int r0 = tr << 6, c0 = tc << 6;
    const int cc = (t & 15) << 2;
    #pragma unroll
    for (int q = 0; q < 4; ++q) {
        const int rr = (t >> 4) + (q << 4);
        const u16x4 v = __builtin_nontemporal_load(
            (const u16x4*)&src[(size_t)(r0 + rr) * 4096 + c0 + cc]);
        tile[rr][cc + 0] = v[0]; tile[rr][cc + 1] = v[1];
        tile[rr][cc + 2] = v[2]; tile[rr][cc + 3] = v[3];
    }
    __syncthreads();
    #pragma unroll
    for (int q = 0; q < 4; ++q) {
        const int rr = (t >> 4) + (q << 4);
        f32x4 o;
        o[0] = __uint_as_float((unsigned)tile[cc + 0][rr] << 16);
        o[1] = __uint_as_float((unsigned)tile[cc + 1][rr] << 16);
        o[2] = __uint_as_float((unsigned)tile[cc + 2][rr] << 16);
        o[3] = __uint_as_float((unsigned)tile[cc + 3][rr] << 16);
        __builtin_nontemporal_store(o, (f32x4*)&dst[(size_t)(c0 + rr) * 4096 + r0 + cc]);
    }
}

// ---- Kernel 2: main GEMM. B staged through LDS with SEQUENTIAL weight reads. ----
__global__ __launch_bounds__(256, 2)
void lc_main(const unsigned short* __restrict__ xT, const float* __restrict__ wt,
             unsigned short* __restrict__ outT) {
    __shared__ __align__(16) unsigned short A[64 * ASTR];   // 37888 B
    __shared__ __align__(16) unsigned short B[32 * BSTR];   // 18944 B

    const int bid = blockIdx.x;
    const int swz = (bid & 7) * 512 + (bid >> 3);   // bijective XCD remap
    const int h = swz >> 6, wq = swz & 63;
    const int loc = (h << 6) + wq;

    const int t    = threadIdx.x;
    const int lane = t & 63;
    const int wv   = t >> 6;
    const int l15  = lane & 15;
    const int kg   = lane >> 4;

    const float* wloc = wt + (size_t)loc * 36864;

    // B staging map: thread t -> chunk row bco (0..31), granule oct (0..7)
    const int bco = t >> 3;
    const int oct = t & 7;

    // A staging map: b_st (0..63), cig (0..3)
    const int b_st = t >> 2;
    const int cig  = t & 3;

    // taps
    int tapr[9]; int tv[9];
    #pragma unroll
    for (int tap = 0; tap < 9; ++tap) {
        const int y = h + tap / 3 - 1, xx = wq + tap % 3 - 1;
        const int ok = ((unsigned)y < 64u) && ((unsigned)xx < 64u);
        tv[tap] = ok;
        tapr[tap] = ok ? ((y << 6) + xx) : 0;
    }

    f32x4 acc[2][2] = {{{0.f,0.f,0.f,0.f},{0.f,0.f,0.f,0.f}},
                       {{0.f,0.f,0.f,0.f},{0.f,0.f,0.f,0.f}}};
    f32x4  br[9];
    bf16x8 xr[9];

    auto issueB = [&](int hs, int ch) {
        const float* s = wloc + (size_t)(ch * 32 + bco) * 576 + hs * 288 + (oct << 2);
        #pragma unroll
        for (int i = 0; i < 9; ++i)
            br[i] = __builtin_nontemporal_load((const f32x4*)(s + (i << 5)));
    };
    auto writeB = [&]() {
        unsigned short* d = &B[bco * BSTR + (oct << 2)];
        #pragma unroll
        for (int i = 0; i < 9; ++i) {
            u16x4 o;
            o[0] = f2bf(br[i][0]); o[1] = f2bf(br[i][1]);
            o[2] = f2bf(br[i][2]); o[3] = f2bf(br[i][3]);
            *(u16x4*)&d[i << 5] = o;
        }
    };
    auto issueA = [&](int hs) {
        #pragma unroll
        for (int tap = 0; tap < 9; ++tap) {
            bf16x8 v = {0,0,0,0,0,0,0,0};
            if (tv[tap])
                v = *(const bf16x8*)&xT[(size_t)tapr[tap] * 4096 + (b_st << 6)
                                        + hs * 32 + (cig << 3)];
            xr[tap] = v;
        }
    };
    auto writeA = [&]() {
        unsigned short* d = &A[b_st * ASTR + cig * 72];
        #pragma unroll
        for (int tap = 0; tap < 9; ++tap)
            #pragma unroll
            for (int j = 0; j < 8; ++j)
                d[j * 9 + tap] = (unsigned short)xr[tap][j];
    };
    auto compute = [&](int ch) {
        const int arow0 = ((wv >> 1) * 32 + l15) * ASTR + (kg << 3);
        const int brow  = ((wv & 1) * 16 + l15) * BSTR + (kg << 3);
        #pragma unroll
        for (int ksl = 0; ksl < 9; ++ksl) {
            const int kk = ksl * 32;
            const bf16x8 bfr = *(const bf16x8*)&B[brow + kk];
            const bf16x8 a0  = *(const bf16x8*)&A[arow0 + kk];
            const bf16x8 a1  = *(const bf16x8*)&A[arow0 + 16 * ASTR + kk];
            acc[0][ch] = __builtin_amdgcn_mfma_f32_16x16x32_bf16(a0, bfr, acc[0][ch], 0, 0, 0);
            acc[1][ch] = __builtin_amdgcn_mfma_f32_16x16x32_bf16(a1, bfr, acc[1][ch], 0, 0, 0);
        }
    };

    // ---- T14 pipeline: issue one phase ahead of every LDS-write phase ----
    issueB(0, 0); issueA(0);
    writeB(); writeA();
    issueB(0, 1);
    __syncthreads();
    compute(0);                       // (hs0, ch0); B01 in flight
    __syncthreads();
    writeB(); issueB(1, 0); issueA(1);
    __syncthreads();
    compute(1);                       // (hs0, ch1); B10+A1 in flight
    __syncthreads();
    writeB(); writeA();
    issueB(1, 1);
    __syncthreads();
    compute(0);                       // (hs1, ch0); B11 in flight
    __syncthreads();
    writeB();
    __syncthreads();
    compute(1);                       // (hs1, ch1)

    // epilogue: outT[hw][b*64+co] bf16
    const size_t obase = (size_t)loc * 4096;
    #pragma unroll
    for (int m2 = 0; m2 < 2; ++m2)
        #pragma unroll
        for (int ch = 0; ch < 2; ++ch)
            #pragma unroll
            for (int j = 0; j < 4; ++j) {
                const int b  = (wv >> 1) * 32 + m2 * 16 + (kg << 2) + j;
                const int co = ch * 32 + (wv & 1) * 16 + l15;
                outT[obase + (b << 6) + co] = f2bf(fmaxf(acc[m2][ch][j], 0.f));
            }
}

// ---- Fallback (round-2 proven): direct gather + scattered write ----
__global__ __launch_bounds__(256, 4)
void lc_mfma(const float* __restrict__ x, const float* __restrict__ wt,
             float* __restrict__ out) {
    __shared__ __align__(16) unsigned short A[64 * LSTR];
    const int bid = blockIdx.x;
    const int swz = (bid & 7) * 512 + (bid >> 3);
    const int h   = swz >> 6;
    const int wq  = swz & 63;
    const int t    = threadIdx.x;
    const int lane = t & 63;
    const int wv   = t >> 6;
    const float* wloc = wt + (size_t)((h << 6) + wq) * 36864;
    const int co = (wv << 4) + (lane & 15);
    const int kg = lane >> 4;
    const float* wrow = wloc + co * 576 + (kg << 3);
    f32x4 acc[4] = {{0.f,0.f,0.f,0.f},{0.f,0.f,0.f,0.f},
                    {0.f,0.f,0.f,0.f},{0.f,0.f,0.f,0.f}};
    const int cil = t & 31;
    const int bro = t >> 5;
    for (int hs = 0; hs < 2; ++hs) {
        const int kbase = hs * 288;
        f32x4 pb[3][2];
        pb[0][0] = __builtin_nontemporal_load((const f32x4*)(wrow + kbase + 0));
        pb[0][1] = __builtin_nontemporal_load((const f32x4*)(wrow + kbase + 4));
        pb[1][0] = __builtin_nontemporal_load((const f32x4*)(wrow + kbase + 32));
        pb[1][1] = __builtin_nontemporal_load((const f32x4*)(wrow + kbase + 36));
        {
            const int ci = (hs << 5) + cil;
            for (int p = 0; p < 8; ++p) {
                const int b = (p << 3) + bro;
                const float* xb = x + ((size_t)((b << 6) + ci) << 12);
                unsigned short* dst = &A[b * LSTR + cil * 9];
                #pragma unroll
                for (int dy = 0; dy < 3; ++dy) {
                    const int y = h + dy - 1;
                    const bool yok = (unsigned)y < 64u;
                    #pragma unroll
                    for (int dx = 0; dx < 3; ++dx) {
                        const int xx = wq + dx - 1;
                        float v = 0.f;
                        if (yok && (unsigned)xx < 64u) v = xb[(y << 6) + xx];
                        dst[dy * 3 + dx] = f2bf(v);
                    }
                }
            }
        }
        __syncthreads();
        #pragma unroll
        for (int ks = 0; ks < 9; ++ks) {
            const int cur = ks % 3;
            const int nxt = (ks + 2) % 3;
            if (ks < 7) {
                const float* np = wrow + kbase + (ks + 2) * 32;
                pb[nxt][0] = __builtin_nontemporal_load((const f32x4*)(np));
                pb[nxt][1] = __builtin_nontemporal_load((const f32x4*)(np + 4));
            }
            const f32x4 lo = pb[cur][0], hi = pb[cur][1];
            bf16x8 bf;
            bf[0] = (short)f2bf(lo[0]); bf[1] = (short)f2bf(lo[1]);
            bf[2] = (short)f2bf(lo[2]); bf[3] = (short)f2bf(lo[3]);
            bf[4] = (short)f2bf(hi[0]); bf[5] = (short)f2bf(hi[1]);
            bf[6] = (short)f2bf(hi[2]); bf[7] = (short)f2bf(hi[3]);
            const int kk = (ks << 5) + (kg << 3);
            #pragma unroll
            for (int mt = 0; mt < 4; ++mt) {
                const bf16x8 afl = *(const bf16x8*)&A[((mt << 4) + (lane & 15)) * LSTR + kk];
                acc[mt] = __builtin_amdgcn_mfma_f32_16x16x32_bf16(afl, bf, acc[mt], 0, 0, 0);
            }
        }
        __syncthreads();
    }
    const int rg = lane >> 4;
    #pragma unroll
    for (int mt = 0; mt < 4; ++mt) {
        #pragma unroll
        for (int j = 0; j < 4; ++j) {
            const int b = (mt << 4) + (rg << 2) + j;
            out[(size_t)((b << 6) + co) * 4096 + (h << 6) + wq] = fmaxf(acc[mt][j], 0.f);
        }
    }
}

extern "C" void kernel_launch(void* const* d_in, const int* in_sizes, int n_in,
                              void* d_out, int out_size, void* d_ws, size_t ws_size,
                              hipStream_t stream) {
    const float* x  = (const float*)d_in[0];
    const float* wt = (const float*)d_in[1];
    float* out = (float*)d_out;

    const size_t xT_bytes   = (size_t)4096 * 4096 * 2;
    const size_t outT_bytes = (size_t)4096 * 4096 * 2;

    if (ws_size >= xT_bytes + outT_bytes) {
        unsigned short* xT   = (unsigned short*)d_ws;
        unsigned short* outT = (unsigned short*)((char*)d_ws + xT_bytes);
        hipLaunchKernelGGL(transpose_in, dim3(4096), dim3(256), 0, stream, x, xT);
        hipLaunchKernelGGL(lc_main, dim3(4096), dim3(256), 0, stream, xT, wt, outT);
        hipLaunchKernelGGL(transpose_out_bf, dim3(4096), dim3(256), 0, stream, outT, out);
    } else {
        hipLaunchKernelGGL(lc_mfma, dim3(4096), dim3(256), 0, stream, x, wt, out);
    }
}